// Round 14
// baseline (3527.726 us; speedup 1.0000x reference)
//
#include <hip/hip_runtime.h>
#include <math.h>

#define T_LEN 8192
#define NTRIALS 1024
#define TN ((size_t)T_LEN * NTRIALS)
#define KLEN 50
#define WCHUNK 32                // output rows per WAVE
#define BROWS 256                // output rows per BLOCK (8 waves x 32)
#define NMC (T_LEN / BROWS)      // 32 macro-chunks
#define FARW 256                 // unchecked f32 warmup
#define NEARW 192                // checked f64 warmup
#define WARM (FARW + NEARW)      // 448
#define GP 32                    // rows per prefetch group
#define BAND 1e-4f               // ambiguity band (f32 thr err <= 3e-5)

// ---------------------------------------------------------------------------
// Kernel 1 (fused prep, f32 thresholds - the R12 version that passed): one
// block per time-row j; every thread redundantly computes basc_j (50-tap f64
// conv), then converts its 4 rand elems to f32 thresholds.
// ---------------------------------------------------------------------------
__global__ __launch_bounds__(256) void prep_fused_kernel(
    const float* __restrict__ t, const float* __restrict__ stim,
    const float* __restrict__ bias, const float* __restrict__ k_stim,
    const float* __restrict__ hist_w, const float* __restrict__ hist_tau,
    const float* __restrict__ rnd, double* __restrict__ dparams,
    double* __restrict__ basc, float* __restrict__ bascf,
    float* __restrict__ thr32) {
  const int j = blockIdx.x;
  const int tid = threadIdx.x;
  const double dt = (double)t[1] - (double)t[0];

  double acc = 0.0;
  if (j > 0) {
    int n = j - 1;
    int mmax = n < (KLEN - 1) ? n : (KLEN - 1);
    for (int m = 0; m <= mmax; ++m)
      acc += (double)k_stim[m] * (double)stim[n - m];
  }
  double b64 = (double)bias[0] + (j > 0 ? dt * acc : 0.0);
  float bf = (float)b64;

  if (tid == 0) {
    basc[j] = b64;
    bascf[j] = bf;
    if (j == 0) {
      dparams[0] = exp(-dt / (double)hist_tau[0]);
      dparams[1] = exp(-dt / (double)hist_tau[1]);
      dparams[2] = (double)hist_w[0];
      dparams[3] = (double)hist_w[1];
      dparams[4] = dt;
    }
  }

  const float dtf = (float)dt;
  size_t m = (size_t)j * NTRIALS + (size_t)tid * 4;
  float4 r4 = *reinterpret_cast<const float4*>(rnd + m);
  float4 o;
  o.x = logf(-log1pf(-r4.x) / dtf) - bf;
  o.y = logf(-log1pf(-r4.y) / dtf) - bf;
  o.z = logf(-log1pf(-r4.z) / dtf) - bf;
  o.w = logf(-log1pf(-r4.w) / dtf) - bf;
  *reinterpret_cast<float4*>(thr32 + m) = o;
}

// Rare exact re-decision (band hit ~2e-5/lane-step): f64 ground truth.
__device__ __noinline__ bool decide64(const float* __restrict__ rnd,
                                      const double* __restrict__ basc,
                                      double dt, int j, int i, double h) {
  double r = (double)rnd[(size_t)j * NTRIALS + i];
  double t = log(-log1p(-r) / dt) - basc[j];
  return h > t;
}

// ---------------------------------------------------------------------------
// Kernel 2: speculative scan, issue-dieted + kappa=4. 512 blocks x 512 thr
// (8 waves) = 4096 waves = 4 waves/SIMD, 2 blocks/CU. Wave wv of block
// (mc, tb): independent chain, jstart = mc*256 + wv*32, warmup 448 rows
// (FAR 256 f32 unchecked, NEAR 192 f64 band-checked), OUT 32 + stores.
// Issue diet vs R13: f32 thr (no dequant; bytes proven non-binding R8/12/13),
// f64 weight-select via ONE v_cndmask_b32 on the high dword (f32-widened
// doubles have zero low dword), NEARW 256->192 (residual ~5e-9, ~0.01
// expected flips). Groups of 32 double-buffered in registers as before.
// ---------------------------------------------------------------------------
__global__ __launch_bounds__(512, 4) void spec_scan5_kernel(
    const float* __restrict__ thr, const float* __restrict__ rnd,
    const double* __restrict__ basc, const float* __restrict__ bascf,
    const double* __restrict__ dparams, float* __restrict__ out) {
  const int lane = threadIdx.x & 63;
  const int wv   = threadIdx.x >> 6;   // wave 0..7
  const int tb   = blockIdx.x & 15;    // trial group (low bits -> XCD bind)
  const int mc   = blockIdx.x >> 4;    // macro chunk 0..31
  const int i    = tb * 64 + lane;
  const double d0 = dparams[0], d1 = dparams[1];
  const double w0 = dparams[2], w1 = dparams[3];
  const double dt = dparams[4];
  const float d0f = (float)d0, d1f = (float)d1;
  const float w0f = (float)w0, w1f = (float)w1;
  const int w0hi = __double2hiint(w0);  // low dwords are 0 (f32-widened)
  const int w1hi = __double2hiint(w1);

  const int jstart = mc * BROWS + wv * WCHUNK;
  const int nw    = jstart < WARM ? jstart : WARM;
  const int jw    = jstart - nw;
  const int nearn = nw < NEARW ? nw : NEARW;
  const int farn  = nw - nearn;
  const int j1    = jw + farn;          // NEAR start (multiple of 32)
  const int ngrp  = nw / GP + 1;        // warmup groups + 1 OUT group

  const float* __restrict__ p = thr + i;  // column i, row stride NTRIALS
  float a0 = 0.0f, a1 = 0.0f;   // FAR state (f32)
  double s0 = 0.0, s1 = 0.0;    // NEAR/OUT state (f64)
  float bufA[GP], bufB[GP];

  auto process = [&](int r0, float* buf) {
    if (r0 >= jstart) {
      // ---- OUT: 32 checked steps + stores ----
      float* __restrict__ pll = out + (size_t)r0 * NTRIALS + i;
      float* __restrict__ pmk = pll + TN;
#pragma unroll
      for (int k = 0; k < GP; ++k) {
        double h = s0 + s1;
        float d = (float)h - buf[k];
        bool s = d > 0.0f;
        if (__builtin_expect(fabsf(d) < BAND, 0))
          s = decide64(rnd, basc, dt, r0 + k, i, h);
        pll[(size_t)k * NTRIALS] = (float)h + bascf[r0 + k];
        pmk[(size_t)k * NTRIALS] = s ? 1.0f : 0.0f;
        s0 = fma(d0, s0, __hiloint2double(s ? w0hi : 0, 0));
        s1 = fma(d1, s1, __hiloint2double(s ? w1hi : 0, 0));
      }
    } else if (r0 >= j1) {
      // ---- NEAR: f64 state, band-checked exact ----
      if (r0 == j1) { s0 = (double)a0; s1 = (double)a1; }
#pragma unroll
      for (int k = 0; k < GP; ++k) {
        double h = s0 + s1;
        float d = (float)h - buf[k];
        bool s = d > 0.0f;
        if (__builtin_expect(fabsf(d) < BAND, 0))
          s = decide64(rnd, basc, dt, r0 + k, i, h);
        s0 = fma(d0, s0, __hiloint2double(s ? w0hi : 0, 0));
        s1 = fma(d1, s1, __hiloint2double(s ? w1hi : 0, 0));
      }
    } else {
      // ---- FAR: f32 state, unchecked ----
#pragma unroll
      for (int k = 0; k < GP; ++k) {
        float h = a0 + a1;
        bool s = h > buf[k];
        a0 = fmaf(d0f, a0, s ? w0f : 0.0f);
        a1 = fmaf(d1f, a1, s ? w1f : 0.0f);
      }
    }
  };

  // preload group 0
#pragma unroll
  for (int k = 0; k < GP; ++k) bufA[k] = p[(size_t)(jw + k) * NTRIALS];
  __builtin_amdgcn_sched_barrier(0);

  int g = 0;
  while (true) {
    // even group -> bufA
    if (g + 1 < ngrp) {
      const int rn = jw + (g + 1) * GP;
#pragma unroll
      for (int k = 0; k < GP; ++k) bufB[k] = p[(size_t)(rn + k) * NTRIALS];
    }
    __builtin_amdgcn_sched_barrier(0);
    process(jw + g * GP, bufA);
    __builtin_amdgcn_sched_barrier(0);
    if (++g >= ngrp) break;
    // odd group -> bufB
    if (g + 1 < ngrp) {
      const int rn = jw + (g + 1) * GP;
#pragma unroll
      for (int k = 0; k < GP; ++k) bufA[k] = p[(size_t)(rn + k) * NTRIALS];
    }
    __builtin_amdgcn_sched_barrier(0);
    process(jw + g * GP, bufB);
    __builtin_amdgcn_sched_barrier(0);
    if (++g >= ngrp) break;
  }
}

// Fallback (small ws): fully inline serial scan, correct but slow.
__global__ __launch_bounds__(64, 1) void glm_scan_inline_kernel(
    const float* __restrict__ rnd, const float* __restrict__ t,
    const float* __restrict__ stim, const float* __restrict__ bias,
    const float* __restrict__ k_stim, const float* __restrict__ hist_w,
    const float* __restrict__ hist_tau, float* __restrict__ out) {
  const int i = blockIdx.x * 64 + threadIdx.x;
  const double dt = (double)t[1] - (double)t[0];
  const double d0 = exp(-dt / (double)hist_tau[0]);
  const double d1 = exp(-dt / (double)hist_tau[1]);
  const double w0 = (double)hist_w[0], w1 = (double)hist_w[1];
  double s0 = 0.0, s1 = 0.0;
  float* __restrict__ out_ll = out;
  float* __restrict__ out_mk = out + TN;
  for (int j = 0; j < T_LEN; ++j) {
    double acc = 0.0;
    if (j > 0) {
      int n = j - 1;
      int mmax = n < (KLEN - 1) ? n : (KLEN - 1);
      for (int m = 0; m <= mmax; ++m)
        acc += (double)k_stim[m] * (double)stim[n - m];
    }
    double b = (double)bias[0] + dt * acc;
    double r = (double)rnd[(size_t)j * NTRIALS + i];
    double th = log(-log1p(-r) / dt) - b;
    double hist = s0 + s1;
    bool spk = hist > th;
    out_ll[(size_t)j * NTRIALS + i] = (float)(b + hist);
    out_mk[(size_t)j * NTRIALS + i] = spk ? 1.0f : 0.0f;
    s0 = fma(d0, s0, spk ? w0 : 0.0);
    s1 = fma(d1, s1, spk ? w1 : 0.0);
  }
}

extern "C" void kernel_launch(void* const* d_in, const int* in_sizes, int n_in,
                              void* d_out, int out_size, void* d_ws, size_t ws_size,
                              hipStream_t stream) {
  const float* t        = (const float*)d_in[0];
  const float* stim     = (const float*)d_in[1];
  const float* rnd      = (const float*)d_in[2];
  const float* bias     = (const float*)d_in[3];
  const float* k_stim   = (const float*)d_in[4];
  const float* hist_w   = (const float*)d_in[5];
  const float* hist_tau = (const float*)d_in[6];
  float* out = (float*)d_out;

  char* ws = (char*)d_ws;
  const size_t off_bascf = 64;
  const size_t off_basc  = off_bascf + (size_t)T_LEN * 4;
  const size_t off_thr   = off_basc + (size_t)T_LEN * 8;
  const size_t need_full = off_thr + TN * 4;   // f32 thresholds

  double* dparams = (double*)ws;
  float*  bascf   = (float*)(ws + off_bascf);
  double* basc    = (double*)(ws + off_basc);
  float*  thr32   = (float*)(ws + off_thr);

  if (ws_size >= need_full) {
    prep_fused_kernel<<<T_LEN, 256, 0, stream>>>(
        t, stim, bias, k_stim, hist_w, hist_tau, rnd, dparams, basc, bascf, thr32);
    spec_scan5_kernel<<<NMC * 16, 512, 0, stream>>>(
        thr32, rnd, basc, bascf, dparams, out);
  } else {
    glm_scan_inline_kernel<<<NTRIALS / 64, 64, 0, stream>>>(
        rnd, t, stim, bias, k_stim, hist_w, hist_tau, out);
  }
}

// Round 15
// 100.035 us; speedup vs baseline: 35.2648x; 35.2648x over previous
//
#include <hip/hip_runtime.h>
#include <math.h>

#define T_LEN 8192
#define NTRIALS 1024
#define TN ((size_t)T_LEN * NTRIALS)
#define KLEN 50
#define WCHUNK 32                // output rows per WAVE
#define BROWS 256                // output rows per BLOCK (8 waves x 32)
#define NMC (T_LEN / BROWS)      // 32 macro-chunks
#define FARW 256                 // unchecked f32 warmup
#define NEARW 192                // checked f64 warmup
#define WARM (FARW + NEARW)      // 448
#define GP 32                    // rows per group
#define BAND 1e-4f               // ambiguity band (f32 thr err <= 3e-5)

// ---------------------------------------------------------------------------
// Kernel 1 (fused prep, f32 thresholds - passed R12): one block per time-row
// j; every thread redundantly computes basc_j (50-tap f64 conv), then
// converts its 4 rand elems to f32 thresholds.
// ---------------------------------------------------------------------------
__global__ __launch_bounds__(256) void prep_fused_kernel(
    const float* __restrict__ t, const float* __restrict__ stim,
    const float* __restrict__ bias, const float* __restrict__ k_stim,
    const float* __restrict__ hist_w, const float* __restrict__ hist_tau,
    const float* __restrict__ rnd, double* __restrict__ dparams,
    double* __restrict__ basc, float* __restrict__ bascf,
    float* __restrict__ thr32) {
  const int j = blockIdx.x;
  const int tid = threadIdx.x;
  const double dt = (double)t[1] - (double)t[0];

  double acc = 0.0;
  if (j > 0) {
    int n = j - 1;
    int mmax = n < (KLEN - 1) ? n : (KLEN - 1);
    for (int m = 0; m <= mmax; ++m)
      acc += (double)k_stim[m] * (double)stim[n - m];
  }
  double b64 = (double)bias[0] + (j > 0 ? dt * acc : 0.0);
  float bf = (float)b64;

  if (tid == 0) {
    basc[j] = b64;
    bascf[j] = bf;
    if (j == 0) {
      dparams[0] = exp(-dt / (double)hist_tau[0]);
      dparams[1] = exp(-dt / (double)hist_tau[1]);
      dparams[2] = (double)hist_w[0];
      dparams[3] = (double)hist_w[1];
      dparams[4] = dt;
    }
  }

  const float dtf = (float)dt;
  size_t m = (size_t)j * NTRIALS + (size_t)tid * 4;
  float4 r4 = *reinterpret_cast<const float4*>(rnd + m);
  float4 o;
  o.x = logf(-log1pf(-r4.x) / dtf) - bf;
  o.y = logf(-log1pf(-r4.y) / dtf) - bf;
  o.z = logf(-log1pf(-r4.z) / dtf) - bf;
  o.w = logf(-log1pf(-r4.w) / dtf) - bf;
  *reinterpret_cast<float4*>(thr32 + m) = o;
}

// Rare exact re-decision (band hit ~2e-5/lane-step): f64 ground truth.
__device__ __noinline__ bool decide64(const float* __restrict__ rnd,
                                      const double* __restrict__ basc,
                                      double dt, int j, int i, double h) {
  double r = (double)rnd[(size_t)j * NTRIALS + i];
  double t = log(-log1p(-r) / dt) - basc[j];
  return h > t;
}

// ---------------------------------------------------------------------------
// Kernel 2: speculative scan at kappa=4 with STATIC phase loops (R14 lesson:
// runtime-selected buffers spill to scratch; here one static buf[32], all
// indices compile-time). 512 blocks x 512 thr (8 waves) = 4096 waves =
// 4 waves/SIMD, 2 blocks/CU. Wave wv of block (mc,tb): independent chain,
// jstart = mc*256 + wv*32; warmup 448 rows (FAR 256 f32 unchecked, NEAR 192
// f64 band-checked), OUT 32 + stores. Latency hiding via 4-wave TLP.
// Issue diet: f32 thr; f64 weight-select via one cndmask on the high dword
// (f32-widened doubles have zero low dword).
// ---------------------------------------------------------------------------
__global__ __launch_bounds__(512, 4) void spec_scan6_kernel(
    const float* __restrict__ thr, const float* __restrict__ rnd,
    const double* __restrict__ basc, const float* __restrict__ bascf,
    const double* __restrict__ dparams, float* __restrict__ out) {
  const int lane = threadIdx.x & 63;
  const int wv   = threadIdx.x >> 6;   // wave 0..7
  const int tb   = blockIdx.x & 15;    // trial group (low bits -> XCD bind)
  const int mc   = blockIdx.x >> 4;    // macro chunk 0..31
  const int i    = tb * 64 + lane;
  const double d0 = dparams[0], d1 = dparams[1];
  const double w0 = dparams[2], w1 = dparams[3];
  const double dt = dparams[4];
  const float d0f = (float)d0, d1f = (float)d1;
  const float w0f = (float)w0, w1f = (float)w1;
  const int w0hi = __double2hiint(w0);  // low dwords are 0 (f32-widened)
  const int w1hi = __double2hiint(w1);

  const int jstart = mc * BROWS + wv * WCHUNK;
  const int nw    = jstart < WARM ? jstart : WARM;
  const int jw    = jstart - nw;
  const int nearn = nw < NEARW ? nw : NEARW;
  const int farn  = nw - nearn;

  const float* __restrict__ p = thr + i;  // column i, row stride NTRIALS
  float buf[GP];

  // ---------------- FAR: f32 state, unchecked decisions ----------------
  float a0 = 0.0f, a1 = 0.0f;
  for (int q = 0; q < farn; q += GP) {
    const int r0 = jw + q;
#pragma unroll
    for (int k = 0; k < GP; ++k) buf[k] = p[(size_t)(r0 + k) * NTRIALS];
#pragma unroll
    for (int k = 0; k < GP; ++k) {
      float h = a0 + a1;
      bool s = h > buf[k];
      a0 = fmaf(d0f, a0, s ? w0f : 0.0f);
      a1 = fmaf(d1f, a1, s ? w1f : 0.0f);
    }
  }

  // ---------------- NEAR: f64 state, band-checked exact ----------------
  double s0 = (double)a0, s1 = (double)a1;
  const int j1 = jw + farn;
  for (int q = 0; q < nearn; q += GP) {
    const int r0 = j1 + q;
#pragma unroll
    for (int k = 0; k < GP; ++k) buf[k] = p[(size_t)(r0 + k) * NTRIALS];
#pragma unroll
    for (int k = 0; k < GP; ++k) {
      double h = s0 + s1;
      float d = (float)h - buf[k];
      bool s = d > 0.0f;
      if (__builtin_expect(fabsf(d) < BAND, 0))
        s = decide64(rnd, basc, dt, r0 + k, i, h);
      s0 = fma(d0, s0, __hiloint2double(s ? w0hi : 0, 0));
      s1 = fma(d1, s1, __hiloint2double(s ? w1hi : 0, 0));
    }
  }

  // ---------------- OUT: 32 checked steps + stores ----------------
  float* __restrict__ pll = out + (size_t)jstart * NTRIALS + i;
  float* __restrict__ pmk = pll + TN;
#pragma unroll
  for (int k = 0; k < GP; ++k) buf[k] = p[(size_t)(jstart + k) * NTRIALS];
#pragma unroll
  for (int k = 0; k < GP; ++k) {
    double h = s0 + s1;
    float d = (float)h - buf[k];
    bool s = d > 0.0f;
    if (__builtin_expect(fabsf(d) < BAND, 0))
      s = decide64(rnd, basc, dt, jstart + k, i, h);
    pll[(size_t)k * NTRIALS] = (float)h + bascf[jstart + k];
    pmk[(size_t)k * NTRIALS] = s ? 1.0f : 0.0f;
    s0 = fma(d0, s0, __hiloint2double(s ? w0hi : 0, 0));
    s1 = fma(d1, s1, __hiloint2double(s ? w1hi : 0, 0));
  }
}

// Fallback (small ws): fully inline serial scan, correct but slow.
__global__ __launch_bounds__(64, 1) void glm_scan_inline_kernel(
    const float* __restrict__ rnd, const float* __restrict__ t,
    const float* __restrict__ stim, const float* __restrict__ bias,
    const float* __restrict__ k_stim, const float* __restrict__ hist_w,
    const float* __restrict__ hist_tau, float* __restrict__ out) {
  const int i = blockIdx.x * 64 + threadIdx.x;
  const double dt = (double)t[1] - (double)t[0];
  const double d0 = exp(-dt / (double)hist_tau[0]);
  const double d1 = exp(-dt / (double)hist_tau[1]);
  const double w0 = (double)hist_w[0], w1 = (double)hist_w[1];
  double s0 = 0.0, s1 = 0.0;
  float* __restrict__ out_ll = out;
  float* __restrict__ out_mk = out + TN;
  for (int j = 0; j < T_LEN; ++j) {
    double acc = 0.0;
    if (j > 0) {
      int n = j - 1;
      int mmax = n < (KLEN - 1) ? n : (KLEN - 1);
      for (int m = 0; m <= mmax; ++m)
        acc += (double)k_stim[m] * (double)stim[n - m];
    }
    double b = (double)bias[0] + dt * acc;
    double r = (double)rnd[(size_t)j * NTRIALS + i];
    double th = log(-log1p(-r) / dt) - b;
    double hist = s0 + s1;
    bool spk = hist > th;
    out_ll[(size_t)j * NTRIALS + i] = (float)(b + hist);
    out_mk[(size_t)j * NTRIALS + i] = spk ? 1.0f : 0.0f;
    s0 = fma(d0, s0, spk ? w0 : 0.0);
    s1 = fma(d1, s1, spk ? w1 : 0.0);
  }
}

extern "C" void kernel_launch(void* const* d_in, const int* in_sizes, int n_in,
                              void* d_out, int out_size, void* d_ws, size_t ws_size,
                              hipStream_t stream) {
  const float* t        = (const float*)d_in[0];
  const float* stim     = (const float*)d_in[1];
  const float* rnd      = (const float*)d_in[2];
  const float* bias     = (const float*)d_in[3];
  const float* k_stim   = (const float*)d_in[4];
  const float* hist_w   = (const float*)d_in[5];
  const float* hist_tau = (const float*)d_in[6];
  float* out = (float*)d_out;

  char* ws = (char*)d_ws;
  const size_t off_bascf = 64;
  const size_t off_basc  = off_bascf + (size_t)T_LEN * 4;
  const size_t off_thr   = off_basc + (size_t)T_LEN * 8;
  const size_t need_full = off_thr + TN * 4;   // f32 thresholds

  double* dparams = (double*)ws;
  float*  bascf   = (float*)(ws + off_bascf);
  double* basc    = (double*)(ws + off_basc);
  float*  thr32   = (float*)(ws + off_thr);

  if (ws_size >= need_full) {
    prep_fused_kernel<<<T_LEN, 256, 0, stream>>>(
        t, stim, bias, k_stim, hist_w, hist_tau, rnd, dparams, basc, bascf, thr32);
    spec_scan6_kernel<<<NMC * 16, 512, 0, stream>>>(
        thr32, rnd, basc, bascf, dparams, out);
  } else {
    glm_scan_inline_kernel<<<NTRIALS / 64, 64, 0, stream>>>(
        rnd, t, stim, bias, k_stim, hist_w, hist_tau, out);
  }
}